// Round 6
// baseline (1571.372 us; speedup 1.0000x reference)
//
#include <hip/hip_runtime.h>

#define N_NODES 100000
#define E_EDGES 3200000
#define IN_F 128
#define ATT 128
#define HEADS 8
#define DK 16
#define SLOPE 0.2f
#define NH (N_NODES * HEADS)   // 800000

// ---------------------------------------------------------------------------
// K1: wx = x @ W   (100000x128 @ 128x128, fp32 vector FMA)
//     + fused epilogue: s_src[n][h] = sum_k wx[n][h*16+k]*a1[k], s_dst with a2
// ---------------------------------------------------------------------------
__global__ __launch_bounds__(256) void gemm_s_kernel(
    const float* __restrict__ x, const float* __restrict__ W,
    const float* __restrict__ a, float* __restrict__ wx,
    float* __restrict__ s_src, float* __restrict__ s_dst)
{
    __shared__ float xs[8][128];   // [k][row] transposed x tile
    __shared__ float Ws[8][128];   // [k][col]

    const int tid = threadIdx.x;
    const int ty  = tid >> 4;      // 0..15  -> row group (8 rows)
    const int tx  = tid & 15;      // 0..15  -> col group (8 cols)
    const int row0 = blockIdx.x * 128;

    float acc[8][8];
#pragma unroll
    for (int i = 0; i < 8; i++)
#pragma unroll
        for (int j = 0; j < 8; j++) acc[i][j] = 0.f;

    const int lrow  = tid >> 1;        // 0..127 row for x staging
    const int khalf = (tid & 1) * 4;   // 0 or 4
    const int wkk   = tid >> 5;        // 0..7 k-row for W staging
    const int wc    = (tid & 31) * 4;  // col*4

    for (int k0 = 0; k0 < IN_F; k0 += 8) {
        float4 xv = make_float4(0.f, 0.f, 0.f, 0.f);
        const int grow = row0 + lrow;
        if (grow < N_NODES)
            xv = *(const float4*)(x + (size_t)grow * IN_F + k0 + khalf);
        const float4 wv = *(const float4*)(W + (size_t)(k0 + wkk) * ATT + wc);

        __syncthreads();   // previous iter's reads done
        xs[khalf + 0][lrow] = xv.x;
        xs[khalf + 1][lrow] = xv.y;
        xs[khalf + 2][lrow] = xv.z;
        xs[khalf + 3][lrow] = xv.w;
        *(float4*)(&Ws[wkk][wc]) = wv;
        __syncthreads();

#pragma unroll
        for (int kk = 0; kk < 8; kk++) {
            float av[8], bv[8];
            *(float4*)(av)     = *(const float4*)(&xs[kk][ty * 8]);
            *(float4*)(av + 4) = *(const float4*)(&xs[kk][ty * 8 + 4]);
            *(float4*)(bv)     = *(const float4*)(&Ws[kk][tx * 8]);
            *(float4*)(bv + 4) = *(const float4*)(&Ws[kk][tx * 8 + 4]);
#pragma unroll
            for (int r = 0; r < 8; r++)
#pragma unroll
                for (int c = 0; c < 8; c++)
                    acc[r][c] = fmaf(av[r], bv[c], acc[r][c]);
        }
    }

    const int koff = (tx & 1) * 8;
    const int head = tx >> 1;
    float a1[8], a2[8];
#pragma unroll
    for (int c = 0; c < 8; c++) {
        a1[c] = a[koff + c];
        a2[c] = a[DK + koff + c];
    }

#pragma unroll
    for (int r = 0; r < 8; r++) {
        const int grow = row0 + ty * 8 + r;
        const bool ok = (grow < N_NODES);
        if (ok) {
            *(float4*)(wx + (size_t)grow * ATT + tx * 8) =
                make_float4(acc[r][0], acc[r][1], acc[r][2], acc[r][3]);
            *(float4*)(wx + (size_t)grow * ATT + tx * 8 + 4) =
                make_float4(acc[r][4], acc[r][5], acc[r][6], acc[r][7]);
        }
        float p1 = 0.f, p2 = 0.f;
#pragma unroll
        for (int c = 0; c < 8; c++) {
            p1 = fmaf(acc[r][c], a1[c], p1);
            p2 = fmaf(acc[r][c], a2[c], p2);
        }
        p1 += __shfl_xor(p1, 1);
        p2 += __shfl_xor(p2, 1);
        if (((tx & 1) == 0) && ok) {
            s_src[(size_t)grow * HEADS + head] = p1;
            s_dst[(size_t)grow * HEADS + head] = p2;
        }
    }
}

// ---------------------------------------------------------------------------
// K0: zero the denoms accumulator (NH floats)
// ---------------------------------------------------------------------------
__global__ __launch_bounds__(256) void zero_kernel(float4* __restrict__ p)
{
    const int i = blockIdx.x * 256 + threadIdx.x;
    if (i < NH / 4) p[i] = make_float4(0.f, 0.f, 0.f, 0.f);
}

// ---------------------------------------------------------------------------
// K2: fused edge pass (e-order, 2 edges/thread).
//  - coalesced src/dst reads
//  - 2 divergent line-events/edge: s_src[src] row + s_dst[dst] row (both
//    tables 3.2 MB, L2-resident)
//  - ex = exp(leakyrelu(score)) written to att COALESCED (e-order; this is
//    what R3/R4's scattered writes could not do)
//  - denom accumulated with fire-and-forget device-scope fp32 atomics
//    (proven correct in R3's flush path). No binning, no hist/scan/scatter.
// ---------------------------------------------------------------------------
__global__ __launch_bounds__(256) void edge_fused_kernel(
    const int* __restrict__ src, const int* __restrict__ dst,
    const float* __restrict__ s_src, const float* __restrict__ s_dst,
    float* __restrict__ denoms, float* __restrict__ att)
{
    const int e0 = (blockIdx.x * 256 + threadIdx.x) * 2;
    if (e0 >= E_EDGES) return;
    const int2 sp = *(const int2*)(src + e0);
    const int2 dp = *(const int2*)(dst + e0);

    // issue all divergent gathers first (4 requests, 4 lines in flight)
    const float4* ps0 = (const float4*)(s_src + (size_t)sp.x * HEADS);
    const float4* ps1 = (const float4*)(s_src + (size_t)sp.y * HEADS);
    const float4* pd0 = (const float4*)(s_dst + (size_t)dp.x * HEADS);
    const float4* pd1 = (const float4*)(s_dst + (size_t)dp.y * HEADS);
    const float4 xa0 = ps0[0], xa1 = ps0[1];
    const float4 ya0 = ps1[0], ya1 = ps1[1];
    const float4 xb0 = pd0[0], xb1 = pd0[1];
    const float4 yb0 = pd1[0], yb1 = pd1[1];

    const float s0[8] = {xa0.x + xb0.x, xa0.y + xb0.y, xa0.z + xb0.z, xa0.w + xb0.w,
                         xa1.x + xb1.x, xa1.y + xb1.y, xa1.z + xb1.z, xa1.w + xb1.w};
    const float s1[8] = {ya0.x + yb0.x, ya0.y + yb0.y, ya0.z + yb0.z, ya0.w + yb0.w,
                         ya1.x + yb1.x, ya1.y + yb1.y, ya1.z + yb1.z, ya1.w + yb1.w};
    float ex0[8], ex1[8];
#pragma unroll
    for (int h = 0; h < 8; h++) {
        float v = s0[h]; v = v > 0.f ? v : SLOPE * v;
        ex0[h] = __expf(v);
        float u = s1[h]; u = u > 0.f ? u : SLOPE * u;
        ex1[h] = __expf(u);
    }

    // coalesced numerator write (64 B per thread, consecutive threads contiguous)
    float4* pa = (float4*)(att + (size_t)e0 * HEADS);
    pa[0] = make_float4(ex0[0], ex0[1], ex0[2], ex0[3]);
    pa[1] = make_float4(ex0[4], ex0[5], ex0[6], ex0[7]);
    pa[2] = make_float4(ex1[0], ex1[1], ex1[2], ex1[3]);
    pa[3] = make_float4(ex1[4], ex1[5], ex1[6], ex1[7]);

    // fire-and-forget scattered denom atomics (performed at L2, no round-trip)
    float* q0 = denoms + (size_t)sp.x * HEADS;
    float* q1 = denoms + (size_t)sp.y * HEADS;
#pragma unroll
    for (int h = 0; h < 8; h++) {
        unsafeAtomicAdd(q0 + h, ex0[h]);
        unsafeAtomicAdd(q1 + h, ex1[h]);
    }
}

// ---------------------------------------------------------------------------
// K3: rdenom[i] = 1 / denoms[i]   (coalesced elementwise)
// ---------------------------------------------------------------------------
__global__ __launch_bounds__(256) void reduce_recip_kernel(
    const float* __restrict__ denoms, float* __restrict__ rdenom)
{
    const int i = blockIdx.x * 256 + threadIdx.x;
    if (i >= NH) return;
    rdenom[i] = __frcp_rn(denoms[i]);
}

// ---------------------------------------------------------------------------
// K4: att[e][h] *= rdenom[src[e]][h]   (att holds numerators)
//     coalesced att read/write + src read; ONE rdenom line-event per edge.
// ---------------------------------------------------------------------------
__global__ __launch_bounds__(256) void norm_mul_kernel(
    const int* __restrict__ src, const float* __restrict__ rdenom,
    float* __restrict__ att)
{
    const int e0 = (blockIdx.x * 256 + threadIdx.x) * 2;
    if (e0 >= E_EDGES) return;
    const int2 sp = *(const int2*)(src + e0);

    const float4* r0 = (const float4*)(rdenom + (size_t)sp.x * HEADS);
    const float4* r1 = (const float4*)(rdenom + (size_t)sp.y * HEADS);
    const float4 ra0 = r0[0], ra1 = r0[1];
    const float4 rb0 = r1[0], rb1 = r1[1];

    float4* pa = (float4*)(att + (size_t)e0 * HEADS);
    float4 x0 = pa[0], x1 = pa[1], x2 = pa[2], x3 = pa[3];

    x0.x *= ra0.x; x0.y *= ra0.y; x0.z *= ra0.z; x0.w *= ra0.w;
    x1.x *= ra1.x; x1.y *= ra1.y; x1.z *= ra1.z; x1.w *= ra1.w;
    x2.x *= rb0.x; x2.y *= rb0.y; x2.z *= rb0.z; x2.w *= rb0.w;
    x3.x *= rb1.x; x3.y *= rb1.y; x3.z *= rb1.z; x3.w *= rb1.w;

    pa[0] = x0; pa[1] = x1; pa[2] = x2; pa[3] = x3;
}

extern "C" void kernel_launch(void* const* d_in, const int* in_sizes, int n_in,
                              void* d_out, int out_size, void* d_ws, size_t ws_size,
                              hipStream_t stream)
{
    const float* x    = (const float*)d_in[0];
    const int*   edge = (const int*)d_in[1];
    const float* W    = (const float*)d_in[2];
    const float* a    = (const float*)d_in[3];

    float* out = (float*)d_out;
    float* att = out;                                 // (E, HEADS)
    float* wx  = out + (size_t)E_EDGES * HEADS;       // (N, ATT)

    float* ws     = (float*)d_ws;
    float* s_src  = ws;                               // NH floats (3.2 MB)
    float* s_dst  = s_src + (size_t)NH;               // NH floats (3.2 MB)
    float* denoms = s_dst + (size_t)NH;               // NH floats (3.2 MB)
    float* rdenom = denoms + (size_t)NH;              // NH floats (3.2 MB)

    const int* src = edge;                 // edge[0][0][:]
    const int* dst = edge + E_EDGES;       // edge[0][1][:]

    zero_kernel<<<(NH / 4 + 255) / 256, 256, 0, stream>>>((float4*)denoms);

    const int gemm_blocks = (N_NODES + 127) / 128;    // 782
    gemm_s_kernel<<<gemm_blocks, 256, 0, stream>>>(x, W, a, wx, s_src, s_dst);

    const int eblocks = (E_EDGES / 2 + 255) / 256;    // 6250
    edge_fused_kernel<<<eblocks, 256, 0, stream>>>(src, dst, s_src, s_dst,
                                                   denoms, att);

    const int nblocks = (NH + 255) / 256;
    reduce_recip_kernel<<<nblocks, 256, 0, stream>>>(denoms, rdenom);

    norm_mul_kernel<<<eblocks, 256, 0, stream>>>(src, rdenom, att);
}

// Round 8
// 527.105 us; speedup vs baseline: 2.9811x; 2.9811x over previous
//
#include <hip/hip_runtime.h>
#include <hip/hip_fp16.h>

#define N_NODES 100000
#define E_EDGES 3200000
#define IN_F 128
#define ATT 128
#define HEADS 8
#define DK 16
#define SLOPE 0.2f
#define NH (N_NODES * HEADS)   // 800000

// Binning parameters
#define CHUNK 448
#define NBINS 224                 // 224*448 = 100352 >= N
#define NS 8                      // splits per bin (grid.y) == private denom copies
#define HB 512                    // hist/scatter blocks
#define EPB 6272                  // edges per hist/scatter block (mult of 4; 512*6272 >= E)

// load a row of 8 halfs (16 B, ONE dwordx4 lane-request) -> 8 floats
static __device__ __forceinline__ void h8_to_f(const __half* p, float* o)
{
    const float4 raw = *(const float4*)p;
    const __half2* h2 = (const __half2*)&raw;
#pragma unroll
    for (int k = 0; k < 4; k++) {
        const float2 f = __half22float2(h2[k]);
        o[2 * k]     = f.x;
        o[2 * k + 1] = f.y;
    }
}

// bf16 (round-to-nearest-even): fp32 exponent RANGE — safe for 1/denom,
// which reaches ~3e-7 (fp16 min normal is 6.1e-5; R7 failed exactly there)
static __device__ __forceinline__ unsigned short f_to_b(float f)
{
    unsigned int u = __float_as_uint(f);
    u += 0x7FFFu + ((u >> 16) & 1u);
    return (unsigned short)(u >> 16);
}

// load a row of 8 bf16 (16 B, ONE dwordx4 lane-request) -> 8 floats
static __device__ __forceinline__ void b8_to_f(const unsigned short* p, float* o)
{
    const uint4 raw = *(const uint4*)p;
    const unsigned int u[4] = {raw.x, raw.y, raw.z, raw.w};
#pragma unroll
    for (int k = 0; k < 4; k++) {
        o[2 * k]     = __uint_as_float(u[k] << 16);
        o[2 * k + 1] = __uint_as_float(u[k] & 0xFFFF0000u);
    }
}

// ---------------------------------------------------------------------------
// K1: wx = x @ W   (100000x128 @ 128x128, fp32 vector FMA)
//     + fused epilogue: s_src16/s_dst16 (fp16 rows; scores are O(15) so fp16
//     is range-safe; same rounded values feed numerator AND denominator)
// ---------------------------------------------------------------------------
__global__ __launch_bounds__(256) void gemm_s_kernel(
    const float* __restrict__ x, const float* __restrict__ W,
    const float* __restrict__ a, float* __restrict__ wx,
    __half* __restrict__ s_src16, __half* __restrict__ s_dst16)
{
    __shared__ float xs[8][128];   // [k][row] transposed x tile
    __shared__ float Ws[8][128];   // [k][col]

    const int tid = threadIdx.x;
    const int ty  = tid >> 4;      // 0..15  -> row group (8 rows)
    const int tx  = tid & 15;      // 0..15  -> col group (8 cols)
    const int row0 = blockIdx.x * 128;

    float acc[8][8];
#pragma unroll
    for (int i = 0; i < 8; i++)
#pragma unroll
        for (int j = 0; j < 8; j++) acc[i][j] = 0.f;

    const int lrow  = tid >> 1;        // 0..127 row for x staging
    const int khalf = (tid & 1) * 4;   // 0 or 4
    const int wkk   = tid >> 5;        // 0..7 k-row for W staging
    const int wc    = (tid & 31) * 4;  // col*4

    for (int k0 = 0; k0 < IN_F; k0 += 8) {
        float4 xv = make_float4(0.f, 0.f, 0.f, 0.f);
        const int grow = row0 + lrow;
        if (grow < N_NODES)
            xv = *(const float4*)(x + (size_t)grow * IN_F + k0 + khalf);
        const float4 wv = *(const float4*)(W + (size_t)(k0 + wkk) * ATT + wc);

        __syncthreads();   // previous iter's reads done
        xs[khalf + 0][lrow] = xv.x;
        xs[khalf + 1][lrow] = xv.y;
        xs[khalf + 2][lrow] = xv.z;
        xs[khalf + 3][lrow] = xv.w;
        *(float4*)(&Ws[wkk][wc]) = wv;
        __syncthreads();

#pragma unroll
        for (int kk = 0; kk < 8; kk++) {
            float av[8], bv[8];
            *(float4*)(av)     = *(const float4*)(&xs[kk][ty * 8]);
            *(float4*)(av + 4) = *(const float4*)(&xs[kk][ty * 8 + 4]);
            *(float4*)(bv)     = *(const float4*)(&Ws[kk][tx * 8]);
            *(float4*)(bv + 4) = *(const float4*)(&Ws[kk][tx * 8 + 4]);
#pragma unroll
            for (int r = 0; r < 8; r++)
#pragma unroll
                for (int c = 0; c < 8; c++)
                    acc[r][c] = fmaf(av[r], bv[c], acc[r][c]);
        }
    }

    const int koff = (tx & 1) * 8;
    const int head = tx >> 1;
    float a1[8], a2[8];
#pragma unroll
    for (int c = 0; c < 8; c++) {
        a1[c] = a[koff + c];
        a2[c] = a[DK + koff + c];
    }

#pragma unroll
    for (int r = 0; r < 8; r++) {
        const int grow = row0 + ty * 8 + r;
        const bool ok = (grow < N_NODES);
        if (ok) {
            *(float4*)(wx + (size_t)grow * ATT + tx * 8) =
                make_float4(acc[r][0], acc[r][1], acc[r][2], acc[r][3]);
            *(float4*)(wx + (size_t)grow * ATT + tx * 8 + 4) =
                make_float4(acc[r][4], acc[r][5], acc[r][6], acc[r][7]);
        }
        float p1 = 0.f, p2 = 0.f;
#pragma unroll
        for (int c = 0; c < 8; c++) {
            p1 = fmaf(acc[r][c], a1[c], p1);
            p2 = fmaf(acc[r][c], a2[c], p2);
        }
        p1 += __shfl_xor(p1, 1);
        p2 += __shfl_xor(p2, 1);
        if (((tx & 1) == 0) && ok) {
            s_src16[(size_t)grow * HEADS + head] = __float2half_rn(p1);
            s_dst16[(size_t)grow * HEADS + head] = __float2half_rn(p2);
        }
    }
}

// ---------------------------------------------------------------------------
// K2a: per-block histogram of src -> chunk bins. counts[c][b] layout
// ---------------------------------------------------------------------------
__global__ __launch_bounds__(256) void hist_kernel(
    const int* __restrict__ src, int* __restrict__ counts)
{
    __shared__ int h[NBINS];
    const int t = threadIdx.x;
    const int b = blockIdx.x;
    for (int i = t; i < NBINS; i += 256) h[i] = 0;
    __syncthreads();

    const int rb = b * EPB;
    const int re = min(rb + EPB, E_EDGES);
    for (int i = rb + t * 4; i < re; i += 256 * 4) {
        const int4 s4 = *(const int4*)(src + i);
        atomicAdd(&h[s4.x / CHUNK], 1);
        atomicAdd(&h[s4.y / CHUNK], 1);
        atomicAdd(&h[s4.z / CHUNK], 1);
        atomicAdd(&h[s4.w / CHUNK], 1);
    }
    __syncthreads();
    for (int i = t; i < NBINS; i += 256) counts[i * HB + b] = h[i];
}

// ---------------------------------------------------------------------------
// K2b: single-block exclusive prefix scan over counts[NBINS*HB] -> offs
// ---------------------------------------------------------------------------
__global__ __launch_bounds__(1024) void scan_kernel(
    const int* __restrict__ counts, int* __restrict__ offs)
{
    __shared__ int part[1024];
    const int t = threadIdx.x;
    const int per = (NBINS * HB) / 1024;   // 112
    const int base = t * per;

    int sum = 0;
    for (int i = 0; i < per; i++) sum += counts[base + i];
    part[t] = sum;
    __syncthreads();

    for (int off = 1; off < 1024; off <<= 1) {
        int v = 0;
        if (t >= off) v = part[t - off];
        __syncthreads();
        if (t >= off) part[t] += v;
        __syncthreads();
    }

    int run = (t == 0) ? 0 : part[t - 1];
    for (int i = 0; i < per; i++) {
        offs[base + i] = run;
        run += counts[base + i];
    }
}

// ---------------------------------------------------------------------------
// K2c: scatter edges into chunk bins (4-B payload).
//      word = (src - lo) << 17 | dst   (sl < 448 -> 9 bits, dst < 2^17)
// ---------------------------------------------------------------------------
__global__ __launch_bounds__(256) void scatter_kernel(
    const int* __restrict__ src, const int* __restrict__ dst,
    const int* __restrict__ offs, unsigned int* __restrict__ binned)
{
    __shared__ int cur[NBINS];
    const int t = threadIdx.x;
    const int b = blockIdx.x;
    for (int i = t; i < NBINS; i += 256) cur[i] = offs[i * HB + b];
    __syncthreads();

    const int rb = b * EPB;
    const int re = min(rb + EPB, E_EDGES);
    for (int i = rb + t * 4; i < re; i += 256 * 4) {
        const int4 s4 = *(const int4*)(src + i);
        const int4 d4 = *(const int4*)(dst + i);
        const int ss[4] = {s4.x, s4.y, s4.z, s4.w};
        const int dd[4] = {d4.x, d4.y, d4.z, d4.w};
#pragma unroll
        for (int j = 0; j < 4; j++) {
            const int c = ss[j] / CHUNK;
            const int pos = atomicAdd(&cur[c], 1);
            binned[pos] = ((unsigned int)(ss[j] - c * CHUNK) << 17) |
                          (unsigned int)dd[j];
        }
    }
}

// ---------------------------------------------------------------------------
// K2d: per-bin denom pass. Block (c, j): split j of chunk c's bin.
//  - s_src16 slice decoded fp16->fp32 into LDS at staging (once per node,
//    not per edge)
//  - per edge: ONE divergent dwordx4 lane-request (s_dst16 16-B row)
//  - flush: coalesced write to private copy denoms[j]
// ---------------------------------------------------------------------------
__global__ __launch_bounds__(256, 5) void denom_binned_kernel(
    const unsigned int* __restrict__ binned, const int* __restrict__ offs,
    const __half* __restrict__ s_src16, const __half* __restrict__ s_dst16,
    float* __restrict__ denoms)   // [NS][NH]
{
    __shared__ float acc[HEADS][CHUNK + 1];   // 14368 B
    __shared__ float ssrc[CHUNK * HEADS];     // 14336 B

    const int t  = threadIdx.x;
    const int c  = blockIdx.x;
    const int j  = blockIdx.y;
    const int lo = c * CHUNK;
    const int hi = min(lo + CHUNK, N_NODES);

    for (int i = t; i < HEADS * (CHUNK + 1); i += 256)
        ((float*)acc)[i] = 0.f;
    {
        // stage + decode: one 16-B row (8 halfs) per node, coalesced
        for (int nd = t; nd < hi - lo; nd += 256) {
            float f[8];
            h8_to_f(s_src16 + (size_t)(lo + nd) * HEADS, f);
            float4* dp = (float4*)(ssrc + nd * HEADS);
            dp[0] = make_float4(f[0], f[1], f[2], f[3]);
            dp[1] = make_float4(f[4], f[5], f[6], f[7]);
        }
    }
    __syncthreads();

    const int start = offs[c * HB];
    const int end   = (c + 1 < NBINS) ? offs[(c + 1) * HB] : E_EDGES;
    const int len   = end - start;
    const int e0 = start + (int)((long long)len * j / NS);
    const int e1 = start + (int)((long long)len * (j + 1) / NS);

    int i = e0 + t;
    bool v0 = i < e1;
    bool v1 = i + 256 < e1;
    unsigned int pw0 = v0 ? binned[i] : 0u;
    unsigned int pw1 = v1 ? binned[i + 256] : 0u;

    while (v0) {
        const unsigned int w0 = pw0;
        const unsigned int w1 = v1 ? pw1 : pw0;   // safe duplicate for tail
        const bool cv1 = v1;

        // prefetch next pair while this pair's gathers are in flight
        i += 512;
        v0 = i < e1;
        v1 = i + 256 < e1;
        if (v0) pw0 = binned[i];
        if (v1) pw1 = binned[i + 256];

        const int sl0 = (int)(w0 >> 17), di0 = (int)(w0 & 0x1FFFFu);
        const int sl1 = (int)(w1 >> 17), di1 = (int)(w1 & 0x1FFFFu);

        // ONE divergent lane-request per edge
        float db0[8], db1[8];
        h8_to_f(s_dst16 + (size_t)di0 * HEADS, db0);
        h8_to_f(s_dst16 + (size_t)di1 * HEADS, db1);

        const float4* qs0 = (const float4*)(ssrc + sl0 * HEADS);
        const float4* qs1 = (const float4*)(ssrc + sl1 * HEADS);
        const float4 xa0 = qs0[0], xa1 = qs0[1];
        const float4 ya0 = qs1[0], ya1 = qs1[1];
        const float sa[8] = {xa0.x, xa0.y, xa0.z, xa0.w, xa1.x, xa1.y, xa1.z, xa1.w};
        const float sb[8] = {ya0.x, ya0.y, ya0.z, ya0.w, ya1.x, ya1.y, ya1.z, ya1.w};

#pragma unroll
        for (int h = 0; h < 8; h++) {
            float v = sa[h] + db0[h]; v = v > 0.f ? v : SLOPE * v;
            atomicAdd(&acc[h][sl0], __expf(v));
        }
        if (cv1) {
#pragma unroll
            for (int h = 0; h < 8; h++) {
                float v = sb[h] + db1[h]; v = v > 0.f ? v : SLOPE * v;
                atomicAdd(&acc[h][sl1], __expf(v));
            }
        }
    }
    __syncthreads();

    // flush: coalesced float4 writes into this split's private copy
    float* outp = denoms + (size_t)j * NH + (size_t)lo * HEADS;
    for (int nd = t; nd < hi - lo; nd += 256) {
        const float4 o0 = make_float4(acc[0][nd], acc[1][nd], acc[2][nd], acc[3][nd]);
        const float4 o1 = make_float4(acc[4][nd], acc[5][nd], acc[6][nd], acc[7][nd]);
        *(float4*)(outp + (size_t)nd * 8)     = o0;
        *(float4*)(outp + (size_t)nd * 8 + 4) = o1;
    }
}

// ---------------------------------------------------------------------------
// K2e: rdb[i] = bf16( 1 / sum_c denoms[c][i] )  — bf16 keeps fp32 RANGE
// ---------------------------------------------------------------------------
__global__ __launch_bounds__(256) void reduce_recip_kernel(
    const float* __restrict__ denoms, unsigned short* __restrict__ rdb)
{
    const int i = blockIdx.x * 256 + threadIdx.x;
    if (i >= NH) return;
    float s = 0.f;
#pragma unroll
    for (int c = 0; c < NS; c++) s += denoms[(size_t)c * NH + i];
    rdb[i] = f_to_b(__frcp_rn(s));
}

// ---------------------------------------------------------------------------
// K3: e-order normalize, 2 edges/thread.
//  Per edge: s_src16 row (1 lane-request) + s_dst16 row (1) + rdb row (1)
//  = 3 divergent lane-requests (was 6 in R5). att write fully coalesced.
//  Same fp16 scores as the denom pass -> rounding cancels in the ratio.
// ---------------------------------------------------------------------------
__global__ __launch_bounds__(256) void norm_e_kernel(
    const int* __restrict__ src, const int* __restrict__ dst,
    const __half* __restrict__ s_src16, const __half* __restrict__ s_dst16,
    const unsigned short* __restrict__ rdb, float* __restrict__ att)
{
    const int e0 = (blockIdx.x * 256 + threadIdx.x) * 2;
    if (e0 >= E_EDGES) return;
    const int2 sp = *(const int2*)(src + e0);
    const int2 dp = *(const int2*)(dst + e0);

    // issue all divergent loads first (6 lane-requests in flight)
    float sa[8], sb[8], d0[8], d1[8], r0[8], r1[8];
    h8_to_f(s_src16 + (size_t)sp.x * HEADS, sa);
    h8_to_f(s_src16 + (size_t)sp.y * HEADS, sb);
    h8_to_f(s_dst16 + (size_t)dp.x * HEADS, d0);
    h8_to_f(s_dst16 + (size_t)dp.y * HEADS, d1);
    b8_to_f(rdb + (size_t)sp.x * HEADS, r0);
    b8_to_f(rdb + (size_t)sp.y * HEADS, r1);

    float o0[8], o1[8];
#pragma unroll
    for (int h = 0; h < 8; h++) {
        float v = sa[h] + d0[h]; v = v > 0.f ? v : SLOPE * v;
        o0[h] = __expf(v) * r0[h];
        float u = sb[h] + d1[h]; u = u > 0.f ? u : SLOPE * u;
        o1[h] = __expf(u) * r1[h];
    }

    float4* pa = (float4*)(att + (size_t)e0 * HEADS);
    pa[0] = make_float4(o0[0], o0[1], o0[2], o0[3]);
    pa[1] = make_float4(o0[4], o0[5], o0[6], o0[7]);
    pa[2] = make_float4(o1[0], o1[1], o1[2], o1[3]);
    pa[3] = make_float4(o1[4], o1[5], o1[6], o1[7]);
}

extern "C" void kernel_launch(void* const* d_in, const int* in_sizes, int n_in,
                              void* d_out, int out_size, void* d_ws, size_t ws_size,
                              hipStream_t stream)
{
    const float* x    = (const float*)d_in[0];
    const int*   edge = (const int*)d_in[1];
    const float* W    = (const float*)d_in[2];
    const float* a    = (const float*)d_in[3];

    float* out = (float*)d_out;
    float* att = out;                                 // (E, HEADS)
    float* wx  = out + (size_t)E_EDGES * HEADS;       // (N, ATT)

    float*  ws      = (float*)d_ws;
    float*  denoms  = ws;                             // NS*NH floats (25.6 MB)
    __half* s_src16 = (__half*)(denoms + (size_t)NS * NH);   // NH halfs (1.6 MB)
    __half* s_dst16 = s_src16 + (size_t)NH;                  // NH halfs (1.6 MB)
    unsigned short* rdb = (unsigned short*)(s_dst16 + (size_t)NH); // NH (1.6 MB)
    int*    counts  = (int*)(rdb + (size_t)NH);       // NBINS*HB ints (458 KB)
    int*    offs    = counts + (size_t)NBINS * HB;    // NBINS*HB ints (458 KB)
    unsigned int* binned = (unsigned int*)(offs + (size_t)NBINS * HB); // E uints

    const int* src = edge;                 // edge[0][0][:]
    const int* dst = edge + E_EDGES;       // edge[0][1][:]

    const int gemm_blocks = (N_NODES + 127) / 128;    // 782
    gemm_s_kernel<<<gemm_blocks, 256, 0, stream>>>(x, W, a, wx, s_src16, s_dst16);

    hist_kernel<<<HB, 256, 0, stream>>>(src, counts);
    scan_kernel<<<1, 1024, 0, stream>>>(counts, offs);
    scatter_kernel<<<HB, 256, 0, stream>>>(src, dst, offs, binned);

    dim3 bgrid(NBINS, NS);                            // 224 x 8 = 1792 blocks
    denom_binned_kernel<<<bgrid, 256, 0, stream>>>(binned, offs, s_src16, s_dst16, denoms);

    const int nblocks = (NH + 255) / 256;
    reduce_recip_kernel<<<nblocks, 256, 0, stream>>>(denoms, rdb);

    const int eblocks = (E_EDGES / 2 + 255) / 256;    // 6250
    norm_e_kernel<<<eblocks, 256, 0, stream>>>(src, dst, s_src16, s_dst16,
                                               rdb, att);
}